// Round 8
// baseline (154.895 us; speedup 1.0000x reference)
//
#include <hip/hip_runtime.h>

#define T_LEN 50
#define I_IN 2
#define HID 4

typedef _Float16 hf2 __attribute__((ext_vector_type(2)));

__device__ __forceinline__ float EXP2(float x){
#if __has_builtin(__builtin_amdgcn_exp2f)
    return __builtin_amdgcn_exp2f(x);
#else
    return exp2f(x);
#endif
}
__device__ __forceinline__ float RCP(float x){
#if __has_builtin(__builtin_amdgcn_rcpf)
    return __builtin_amdgcn_rcpf(x);
#else
    return 1.0f/x;
#endif
}
__device__ __forceinline__ hf2 PK(float a, float b){
#if __has_builtin(__builtin_amdgcn_cvt_pkrtz)
    return __builtin_bit_cast(hf2, __builtin_amdgcn_cvt_pkrtz(a, b));
#else
    hf2 r; r.x = (_Float16)a; r.y = (_Float16)b; return r;
#endif
}
__device__ __forceinline__ float DOT2(hf2 a, hf2 b, float c){
#if __has_builtin(__builtin_amdgcn_fdot2)
    return __builtin_amdgcn_fdot2(a, b, c, false);
#else
    return c + (float)a.x*(float)b.x + (float)a.y*(float)b.y;
#endif
}

// FMA-pipe reciprocal for d >= 1 (denominators are products of (1+2^x), all >= 1
// and finite thanks to the exp clamp): bit-seed + 2 Newton -> ~1e-6 rel.
// Offloads work from the (throughput-limited) trans pipe to the FMA pipe.
__device__ __forceinline__ float frcp(float d){
    float y = __int_as_float(0x7EF0A3D7 - __float_as_int(d));
    y = y * fmaf(-d, y, 2.0f);
    y = y * fmaf(-d, y, 2.0f);
    return y;
}

// quad_perm DPP move on raw bits. Broadcast lane K of quad: CTRL=K*0x55.
template<int CTRL>
__device__ __forceinline__ int qdpp_i(int v){
#if __has_builtin(__builtin_amdgcn_mov_dpp)
    return __builtin_amdgcn_mov_dpp(v, CTRL, 0xF, 0xF, true);
#else
    int lane = threadIdx.x & 63;
    int sel = (CTRL >> (2*(lane & 3))) & 3;
    return __shfl(v, (lane & ~3) + sel, 64);
#endif
}
template<int CTRL>
__device__ __forceinline__ float qdpp(float v){
    return __int_as_float(qdpp_i<CTRL>(__float_as_int(v)));
}
template<int CTRL>
__device__ __forceinline__ hf2 qdpp_h(hf2 v){
    return __builtin_bit_cast(hf2, qdpp_i<CTRL>(__builtin_bit_cast(int, v)));
}

// broadcast+pack: from per-lane h (unit j in lane j of quad) build (h0,h1),(h2,h3)
__device__ __forceinline__ void bpack(float h, hf2& lo, hf2& hi){
    const float hs = qdpp<0xB1>(h);       // neighbor's h
    const hf2 hh = PK(h, hs);             // lane0:(h0,h1) lane2:(h2,h3)
    lo = qdpp_h<0x00>(hh);
    hi = qdpp_h<0xAA>(hh);
}

// Fused LSTM pointwise stage. Hw EXP2 stays on the trans pipe (5/unit-step,
// algebraic minimum); reciprocals moved to the FMA pipe (frcp) to relieve
// the trans-throughput bottleneck identified in r7.
// Gate pre-activations pre-scaled: i,f,o by S1=-log2e; g by S2=-2log2e.
// c' = [c*B*C + (1-q)*A] * rcp(A*B*C)  with p,r,q = 2^{scaled gates}
// h  = (1-u)*rcp((1+s)(1+u)),  s=2^{S1*o}, u=2^{S2*c'}  (clamped, finite-safe)
__device__ __forceinline__ void lstm_act(const float g[4], float& c, float& h){
    const float S2 = -2.8853900817779268f;
    const float p = EXP2(g[0]);
    const float r = EXP2(g[1]);
    const float q = EXP2(g[2]);
    const float A = 1.0f + r;
    const float Bv = 1.0f + p;
    const float Cv = 1.0f + q;
    const float BC = Bv * Cv;
    const float num = fmaf(c, BC, (1.0f - q) * A);
    c = num * frcp(A * BC);
    const float s = EXP2(g[3]);
    const float u = EXP2(fminf(c * S2, 96.0f));
    h = (1.0f - u) * frcp((1.0f + s) * (1.0f + u));
}

struct LaneState {
    hf2 h0p[2], h1p[2];
    float c0, c1, h1, acc;
};

__global__ __launch_bounds__(256) void lstm_fused(
    const float* __restrict__ x,
    const float* __restrict__ Wih0, const float* __restrict__ Whh0,
    const float* __restrict__ bih0, const float* __restrict__ bhh0,
    const float* __restrict__ Wih1, const float* __restrict__ Whh1,
    const float* __restrict__ bih1, const float* __restrict__ bhh1,
    const float* __restrict__ Wout, const float* __restrict__ bout,
    float* __restrict__ out, int B)
{
    __shared__ float wout_s[T_LEN*HID];
    const int tid = threadIdx.x;
    if (tid < T_LEN*HID) wout_s[tid] = Wout[tid];
    __syncthreads();

    const int gtid = blockIdx.x*256 + tid;
    const int q2 = gtid >> 2;          // quad id, owns elements 2*q2, 2*q2+1
    const int j = tid & 3;             // hidden unit owned by this lane
    const int e0 = q2*2;
    if (e0 >= B) return;

    const float S1 = -1.4426950408889634f;   // -log2(e)
    const float S2 = -2.8853900817779268f;   // -2*log2(e)

    // Per-lane weights for unit j (shared by both elements).
    float b0[4], b1[4];
    hf2 wx0p[4], wh0p[4][2], wx1p[4][2], wh1p[4][2];
#pragma unroll
    for (int G = 0; G < 4; ++G){
        const float s = (G == 2) ? S2 : S1;
        const int r = G*4 + j;
        wx0p[G]    = PK(Wih0[r*2+0]*s, Wih0[r*2+1]*s);
        wh0p[G][0] = PK(Whh0[r*4+0]*s, Whh0[r*4+1]*s);
        wh0p[G][1] = PK(Whh0[r*4+2]*s, Whh0[r*4+3]*s);
        wx1p[G][0] = PK(Wih1[r*4+0]*s, Wih1[r*4+1]*s);
        wx1p[G][1] = PK(Wih1[r*4+2]*s, Wih1[r*4+3]*s);
        wh1p[G][0] = PK(Whh1[r*4+0]*s, Whh1[r*4+1]*s);
        wh1p[G][1] = PK(Whh1[r*4+2]*s, Whh1[r*4+3]*s);
        b0[G] = (bih0[r] + bhh0[r])*s;
        b1[G] = (bih1[r] + bhh1[r])*s;
    }

    LaneState sA, sB;
    sA.h0p[0]=hf2{0,0}; sA.h0p[1]=hf2{0,0}; sA.h1p[0]=hf2{0,0}; sA.h1p[1]=hf2{0,0};
    sA.c0=0.f; sA.c1=0.f; sA.h1=0.f; sA.acc=0.f;
    sB = sA;

    const float* xp0 = x + (size_t)e0 * (T_LEN*I_IN);
    const float* xp1 = xp0 + (T_LEN*I_IN);

    // one LSTM step for one element's state
    auto step1 = [&](LaneState& st, hf2 xpk, float wo){
        float g[4];
#pragma unroll
        for (int G = 0; G < 4; ++G){
            float a = DOT2(wx0p[G], xpk, b0[G]);
            a = DOT2(wh0p[G][0], st.h0p[0], a);
            a = DOT2(wh0p[G][1], st.h0p[1], a);
            g[G] = a;
        }
        float h0;
        lstm_act(g, st.c0, h0);
        bpack(h0, st.h0p[0], st.h0p[1]);

#pragma unroll
        for (int G = 0; G < 4; ++G){
            float a = DOT2(wx1p[G][0], st.h0p[0], b1[G]);
            a = DOT2(wx1p[G][1], st.h0p[1], a);
            a = DOT2(wh1p[G][0], st.h1p[0], a);
            a = DOT2(wh1p[G][1], st.h1p[1], a);
            g[G] = a;
        }
        lstm_act(g, st.c1, st.h1);
        bpack(st.h1, st.h1p[0], st.h1p[1]);

        st.acc = fmaf(st.h1, wo, st.acc);
    };

#pragma unroll 5
    for (int tt = 0; tt < T_LEN/2; ++tt){
        const float4 xa = *reinterpret_cast<const float4*>(xp0 + tt*4);
        const float4 xb = *reinterpret_cast<const float4*>(xp1 + tt*4);
        const float wo0 = wout_s[(2*tt)*4 + j];
        const float wo1 = wout_s[(2*tt+1)*4 + j];
        // two independent chains — compiler interleaves within the block
        step1(sA, PK(xa.x, xa.y), wo0);
        step1(sB, PK(xb.x, xb.y), wo0);
        step1(sA, PK(xa.z, xa.w), wo1);
        step1(sB, PK(xb.z, xb.w), wo1);
    }

    // quad reductions
    float a0 = sA.acc, a1 = sB.acc;
    a0 += qdpp<0xB1>(a0);  a0 += qdpp<0x4E>(a0);
    a1 += qdpp<0xB1>(a1);  a1 += qdpp<0x4E>(a1);

    if (j == 0){
        const float z0 = a0 + bout[0];
        const float z1 = a1 + bout[0];
        out[e0]   = RCP(1.0f + EXP2(z0 * S1));
        out[e0+1] = RCP(1.0f + EXP2(z1 * S1));
    }
}

extern "C" void kernel_launch(void* const* d_in, const int* in_sizes, int n_in,
                              void* d_out, int out_size, void* d_ws, size_t ws_size,
                              hipStream_t stream)
{
    const float* x    = (const float*)d_in[0];
    const float* Wih0 = (const float*)d_in[1];
    const float* Whh0 = (const float*)d_in[2];
    const float* bih0 = (const float*)d_in[3];
    const float* bhh0 = (const float*)d_in[4];
    const float* Wih1 = (const float*)d_in[5];
    const float* Whh1 = (const float*)d_in[6];
    const float* bih1 = (const float*)d_in[7];
    const float* bhh1 = (const float*)d_in[8];
    const float* Wout = (const float*)d_in[9];
    const float* bout = (const float*)d_in[10];
    float* out = (float*)d_out;

    const int B = in_sizes[0] / (T_LEN*I_IN);
    const int total = (B/2) * 4;          // 4 lanes per 2 elements
    const int threads = 256;
    const int blocks = (total + threads - 1) / threads;
    lstm_fused<<<blocks, threads, 0, stream>>>(x, Wih0, Whh0, bih0, bhh0,
                                               Wih1, Whh1, bih1, bhh1,
                                               Wout, bout, out, B);
}

// Round 9
// 136.213 us; speedup vs baseline: 1.1372x; 1.1372x over previous
//
#include <hip/hip_runtime.h>

#define T_LEN 50
#define I_IN 2
#define HID 4

typedef float f2 __attribute__((ext_vector_type(2)));

__device__ __forceinline__ float EXP2(float x){
#if __has_builtin(__builtin_amdgcn_exp2f)
    return __builtin_amdgcn_exp2f(x);
#else
    return exp2f(x);
#endif
}
__device__ __forceinline__ float RCP(float x){
#if __has_builtin(__builtin_amdgcn_rcpf)
    return __builtin_amdgcn_rcpf(x);
#else
    return 1.0f/x;
#endif
}

__device__ __forceinline__ f2 splat(float v){ f2 r; r.x = v; r.y = v; return r; }

// packed fp32 fma -> v_pk_fma_f32 (dual-issue fp32; the path to full-rate f32)
__device__ __forceinline__ f2 pkfma(f2 a, f2 b, f2 c){
#if __has_builtin(__builtin_elementwise_fma)
    return __builtin_elementwise_fma(a, b, c);
#else
    f2 r; r.x = fmaf(a.x,b.x,c.x); r.y = fmaf(a.y,b.y,c.y); return r;
#endif
}
__device__ __forceinline__ f2 pkfma_s(float w, f2 x, f2 c){ return pkfma(splat(w), x, c); }

// quad_perm DPP move. Broadcast lane K of quad: CTRL=K*0x55. Swap pairs: 0xB1.
template<int CTRL>
__device__ __forceinline__ int qdpp_i(int v){
#if __has_builtin(__builtin_amdgcn_mov_dpp)
    return __builtin_amdgcn_mov_dpp(v, CTRL, 0xF, 0xF, true);
#else
    int lane = threadIdx.x & 63;
    int sel = (CTRL >> (2*(lane & 3))) & 3;
    return __shfl(v, (lane & ~3) + sel, 64);
#endif
}
template<int CTRL>
__device__ __forceinline__ float qdpp(float v){
    return __int_as_float(qdpp_i<CTRL>(__float_as_int(v)));
}
template<int CTRL>
__device__ __forceinline__ f2 qdpp2(f2 v){
    f2 r; r.x = qdpp<CTRL>(v.x); r.y = qdpp<CTRL>(v.y); return r;
}

// Packed-pair LSTM pointwise stage (two independent batch elements per lane).
// Gate pre-activations pre-scaled: i,f,o by S1=-log2e; g by S2=-2log2e.
// c' = [c*B*C + (1-q)*A] * rcp(A*B*C)  with p,r,q = 2^{scaled gates}
// h  = (1-u)*rcp((1+s)(1+u)),  s=2^{S1*o}, u=2^{S2*c'}  (clamped, finite-safe)
__device__ __forceinline__ void lstm_act2(const f2 g[4], f2& c, f2& h){
    const float S2 = -2.8853900817779268f;
    f2 p, r, q, s;
    p.x = EXP2(g[0].x); p.y = EXP2(g[0].y);
    r.x = EXP2(g[1].x); r.y = EXP2(g[1].y);
    q.x = EXP2(g[2].x); q.y = EXP2(g[2].y);
    s.x = EXP2(g[3].x); s.y = EXP2(g[3].y);
    const f2 one = splat(1.0f);
    const f2 A  = one + r;
    const f2 Bv = one + p;
    const f2 Cv = one + q;
    const f2 BC = Bv * Cv;
    const f2 num = pkfma(c, BC, (one - q) * A);
    const f2 den = A * BC;
    f2 rd; rd.x = RCP(den.x); rd.y = RCP(den.y);
    c = num * rd;
    f2 ua = c * splat(S2);
    ua.x = fminf(ua.x, 96.0f); ua.y = fminf(ua.y, 96.0f);
    f2 u; u.x = EXP2(ua.x); u.y = EXP2(ua.y);
    const f2 dh = (one + s) * (one + u);
    f2 rh; rh.x = RCP(dh.x); rh.y = RCP(dh.y);
    h = (one - u) * rh;
}

__global__ __launch_bounds__(256) void lstm_fused(
    const float* __restrict__ x,
    const float* __restrict__ Wih0, const float* __restrict__ Whh0,
    const float* __restrict__ bih0, const float* __restrict__ bhh0,
    const float* __restrict__ Wih1, const float* __restrict__ Whh1,
    const float* __restrict__ bih1, const float* __restrict__ bhh1,
    const float* __restrict__ Wout, const float* __restrict__ bout,
    float* __restrict__ out, int B)
{
    __shared__ float wout_s[T_LEN*HID];
    const int tid = threadIdx.x;
    if (tid < T_LEN*HID) wout_s[tid] = Wout[tid];
    __syncthreads();

    const int gtid = blockIdx.x*256 + tid;
    const int q2 = gtid >> 2;          // quad id, owns elements 2*q2, 2*q2+1
    const int j = tid & 3;             // hidden unit owned by this lane
    const int e0 = q2*2;
    if (e0 >= B) return;

    const float S1 = -1.4426950408889634f;   // -log2(e)
    const float S2 = -2.8853900817779268f;   // -2*log2(e)

    // Per-lane fp32 weights for unit j (shared by both pair elements).
    float wx0[4][2], wh0[4][4], wx1[4][4], wh1[4][4];
    f2 b0v[4], b1v[4];
#pragma unroll
    for (int G = 0; G < 4; ++G){
        const float s = (G == 2) ? S2 : S1;
        const int r = G*4 + j;
        wx0[G][0] = Wih0[r*2+0]*s;
        wx0[G][1] = Wih0[r*2+1]*s;
#pragma unroll
        for (int k = 0; k < 4; ++k){
            wh0[G][k] = Whh0[r*4+k]*s;
            wx1[G][k] = Wih1[r*4+k]*s;
            wh1[G][k] = Whh1[r*4+k]*s;
        }
        b0v[G] = splat((bih0[r] + bhh0[r])*s);
        b1v[G] = splat((bih1[r] + bhh1[r])*s);
    }

    f2 c0 = splat(0.f), c1 = splat(0.f), acc = splat(0.f);
    f2 h0all[4], h1all[4];
#pragma unroll
    for (int k = 0; k < 4; ++k){ h0all[k] = splat(0.f); h1all[k] = splat(0.f); }

    const float* xp0 = x + (size_t)e0 * (T_LEN*I_IN);
    const float* xp1 = xp0 + (T_LEN*I_IN);

    // one packed step: both elements advance together on pk_fma
    auto step = [&](f2 x0, f2 x1, float wo){
        f2 g[4];
#pragma unroll
        for (int G = 0; G < 4; ++G){
            f2 a = pkfma_s(wx0[G][0], x0, b0v[G]);
            a = pkfma_s(wx0[G][1], x1, a);
#pragma unroll
            for (int k = 0; k < 4; ++k) a = pkfma_s(wh0[G][k], h0all[k], a);
            g[G] = a;
        }
        f2 h0;
        lstm_act2(g, c0, h0);
        h0all[0] = qdpp2<0x00>(h0); h0all[1] = qdpp2<0x55>(h0);
        h0all[2] = qdpp2<0xAA>(h0); h0all[3] = qdpp2<0xFF>(h0);

#pragma unroll
        for (int G = 0; G < 4; ++G){
            f2 a = b1v[G];
#pragma unroll
            for (int k = 0; k < 4; ++k) a = pkfma_s(wx1[G][k], h0all[k], a);
#pragma unroll
            for (int k = 0; k < 4; ++k) a = pkfma_s(wh1[G][k], h1all[k], a);
            g[G] = a;
        }
        f2 h1;
        lstm_act2(g, c1, h1);
        h1all[0] = qdpp2<0x00>(h1); h1all[1] = qdpp2<0x55>(h1);
        h1all[2] = qdpp2<0xAA>(h1); h1all[3] = qdpp2<0xFF>(h1);

        acc = pkfma_s(wo, h1, acc);
    };

#pragma unroll 2
    for (int tt = 0; tt < T_LEN/2; ++tt){
        const float4 xa = *reinterpret_cast<const float4*>(xp0 + tt*4);
        const float4 xb = *reinterpret_cast<const float4*>(xp1 + tt*4);
        const float wo0 = wout_s[(2*tt)*4 + j];
        const float wo1 = wout_s[(2*tt+1)*4 + j];
        f2 x0, x1;
        x0.x = xa.x; x0.y = xb.x;  x1.x = xa.y; x1.y = xb.y;
        step(x0, x1, wo0);
        x0.x = xa.z; x0.y = xb.z;  x1.x = xa.w; x1.y = xb.w;
        step(x0, x1, wo1);
    }

    // quad reductions (both halves in parallel)
    acc += qdpp2<0xB1>(acc);
    acc += qdpp2<0x4E>(acc);

    if (j == 0){
        const float z0 = acc.x + bout[0];
        const float z1 = acc.y + bout[0];
        out[e0]   = RCP(1.0f + EXP2(z0 * S1));
        out[e0+1] = RCP(1.0f + EXP2(z1 * S1));
    }
}

extern "C" void kernel_launch(void* const* d_in, const int* in_sizes, int n_in,
                              void* d_out, int out_size, void* d_ws, size_t ws_size,
                              hipStream_t stream)
{
    const float* x    = (const float*)d_in[0];
    const float* Wih0 = (const float*)d_in[1];
    const float* Whh0 = (const float*)d_in[2];
    const float* bih0 = (const float*)d_in[3];
    const float* bhh0 = (const float*)d_in[4];
    const float* Wih1 = (const float*)d_in[5];
    const float* Whh1 = (const float*)d_in[6];
    const float* bih1 = (const float*)d_in[7];
    const float* bhh1 = (const float*)d_in[8];
    const float* Wout = (const float*)d_in[9];
    const float* bout = (const float*)d_in[10];
    float* out = (float*)d_out;

    const int B = in_sizes[0] / (T_LEN*I_IN);
    const int total = (B/2) * 4;          // 4 lanes per 2 elements
    const int threads = 256;
    const int blocks = (total + threads - 1) / threads;
    lstm_fused<<<blocks, threads, 0, stream>>>(x, Wih0, Whh0, bih0, bhh0,
                                               Wih1, Whh1, bih1, bhh1,
                                               Wout, bout, out, B);
}